// Round 9
// baseline (43.982 us; speedup 1.0000x reference)
//
#include <hip/hip_runtime.h>

#define B_  4
#define NQ_ 256
#define NK_ 512
#define H_  256
#define PADROW 2064            // NK_*4 + 16 floats: breaks 8KB L2-channel stride
#define PR4    (PADROW / 4)    // 516 float4s per kt row

// tanh via exp2, clamped strictly inside (-1,1) so 1+ta*tb > 0 always.
#define TWO_LOG2E 2.8853900817779268f
__device__ __forceinline__ float tanh_fast(float x) {
    float t = __builtin_amdgcn_exp2f(x * TWO_LOG2E);
    float r = __builtin_amdgcn_rcpf(t + 1.0f);
    float y = fmaf(-2.0f, r, 1.0f);
    return fminf(fmaxf(y, -0.99999994f), 0.99999994f);
}

// Both GEMMs, 32x64 tiles, 256 threads, 8 outputs/thread, reg-dbuf staging.
// blocks [0,256):  kt[b][o][k] -> ktTan[b][o>>2][k*4 + (o&3)] (padded rows)
// blocks [256,384): qt[b][q][o] -> tbT[b][q][o] = tanh(qt)
__global__ __launch_bounds__(256)
void gemm_fused(const float* __restrict__ xq, const float* __restrict__ xk,
                const float* __restrict__ w1, const float* __restrict__ w2,
                float* __restrict__ ktTan,   // [B][64][PADROW]
                float* __restrict__ tbT)     // [B][NQ][H]
{
    constexpr int BK = 32;
    const float* A; const float* Bm;
    int m0, n0, bz; bool iskt;
    {
        int id = blockIdx.x;
        if (id < 256) {
            iskt = true;
            bz = id >> 6; int t = id & 63;
            m0 = (t >> 3) * 32; n0 = (t & 7) * 64;
            A = w1; Bm = xk + (long)bz * NK_ * H_;
        } else {
            iskt = false;
            id -= 256;
            bz = id >> 5; int t = id & 31;
            m0 = (t >> 2) * 32; n0 = (t & 3) * 64;
            A = xq + (long)bz * NQ_ * H_; Bm = w2;
        }
    }
    const int lda = H_, ldb = H_;

    __shared__ float As[BK][36];
    __shared__ float Bs[BK][68];

    const int tid  = threadIdx.x;
    const int arow = tid >> 3, ak = (tid & 7) * 4;
    const int brow = tid >> 2, bk = (tid & 3) * 8;
    const int tm = (tid >> 5) * 4;
    const int tn = (tid & 31) * 2;

    float acc[4][2] = {};

    float4 a_r  = *(const float4*)&A [(long)(m0 + arow) * lda + ak];
    float4 b0_r = *(const float4*)&Bm[(long)(n0 + brow) * ldb + bk];
    float4 b1_r = *(const float4*)&Bm[(long)(n0 + brow) * ldb + bk + 4];
    float4 a_n = a_r, b0_n = b0_r, b1_n = b1_r;

    for (int kt = 0; kt < H_; kt += BK) {
        __syncthreads();
        As[ak+0][arow]=a_r.x; As[ak+1][arow]=a_r.y; As[ak+2][arow]=a_r.z; As[ak+3][arow]=a_r.w;
        Bs[bk+0][brow]=b0_r.x; Bs[bk+1][brow]=b0_r.y; Bs[bk+2][brow]=b0_r.z; Bs[bk+3][brow]=b0_r.w;
        Bs[bk+4][brow]=b1_r.x; Bs[bk+5][brow]=b1_r.y; Bs[bk+6][brow]=b1_r.z; Bs[bk+7][brow]=b1_r.w;
        if (kt + BK < H_) {
            a_n  = *(const float4*)&A [(long)(m0 + arow) * lda + kt + BK + ak];
            b0_n = *(const float4*)&Bm[(long)(n0 + brow) * ldb + kt + BK + bk];
            b1_n = *(const float4*)&Bm[(long)(n0 + brow) * ldb + kt + BK + bk + 4];
        }
        __syncthreads();
        #pragma unroll
        for (int kk = 0; kk < BK; ++kk) {
            float4 av = *(const float4*)&As[kk][tm];
            float2 bv = *(const float2*)&Bs[kk][tn];
            float am[4] = {av.x, av.y, av.z, av.w};
            #pragma unroll
            for (int i = 0; i < 4; ++i) {
                acc[i][0] = fmaf(am[i], bv.x, acc[i][0]);
                acc[i][1] = fmaf(am[i], bv.y, acc[i][1]);
            }
        }
        a_r = a_n; b0_r = b0_n; b1_r = b1_n;
    }

    if (iskt) {
        float* cb = ktTan + ((long)bz * 64 + ((m0 + tm) >> 2)) * PADROW;
        #pragma unroll
        for (int j = 0; j < 2; ++j) {
            float4 t4 = { tanh_fast(acc[0][j]), tanh_fast(acc[1][j]),
                          tanh_fast(acc[2][j]), tanh_fast(acc[3][j]) };
            *(float4*)&cb[(n0 + tn + j) * 4] = t4;
        }
    } else {
        #pragma unroll
        for (int i = 0; i < 4; ++i) {
            float2 t2 = { tanh_fast(acc[i][0]), tanh_fast(acc[i][1]) };
            long off = ((long)bz * NQ_ + m0 + tm + i) * H_ + n0 + tn;
            *(float2*)&tbT[off] = t2;
        }
    }
}

// One block per (b, 4 q-rows), 512 threads = one per k.
// Q-side operands staged in LDS once, then read ONE HC AHEAD into ping-pong
// register sets (A/B) so ds_read latency hides under the previous sub-step's
// ~190-cycle compute. kv keeps the 4-deep global prefetch.
__global__ __launch_bounds__(512, 1)
void attn_main(const float4* __restrict__ ktp,  // [B][64][PR4] padded rows
               const float4* __restrict__ tbT,  // [B][NQ][H/4]
               const float4* __restrict__ v4p,  // [H/4]
               float* __restrict__ out)         // [B][NQ][NK]
{
    const int k = threadIdx.x, b = blockIdx.y, q0 = blockIdx.x * 4;

    // stage tb rows q0..q0+3 and v into LDS (5 x 64 float4 = 5KB)
    __shared__ float4 sOp[5 * 64];
    if (k < 320) {
        const int grp = k >> 6, idx = k & 63;
        const float4* src = (grp < 4)
            ? (tbT + ((long)b * NQ_ + q0 + grp) * (H_ / 4))
            : v4p;
        sOp[grp * 64 + idx] = src[idx];
    }
    __syncthreads();

    const float4* kp = ktp + (long)b * 64 * PR4 + k;

    float ac0 = 0.f, ac1 = 0.f, ac2 = 0.f, ac3 = 0.f;

    // kv: 4-deep prefetch queue
    float4 kv0 = kp[0 * PR4], kv1 = kp[1 * PR4], kv2 = kp[2 * PR4], kv3 = kp[3 * PR4];
    float4 nk0 = kv0, nk1 = kv1, nk2 = kv2, nk3 = kv3;

    // operand ping-pong sets (named statically, rule #20)
    float4 tA0 = sOp[0],   tA1 = sOp[64],  tA2 = sOp[128],
           tA3 = sOp[192], vA  = sOp[256];
    float4 tB0, tB1, tB2, tB3, vB;

#define QSTEP(ACC, KV, TB, VV)                                                \
    {                                                                         \
        float d0 = fmaf(KV.x, TB.x, 1.f), d1 = fmaf(KV.y, TB.y, 1.f);         \
        float d2 = fmaf(KV.z, TB.z, 1.f), d3 = fmaf(KV.w, TB.w, 1.f);         \
        float p0 = VV.x * (KV.x + TB.x), p1 = VV.y * (KV.y + TB.y);           \
        float p2 = VV.z * (KV.z + TB.z), p3 = VV.w * (KV.w + TB.w);           \
        float D01 = d0 * d1, D23 = d2 * d3;                                   \
        float N01 = fmaf(p0, d1, p1 * d0);                                    \
        float N23 = fmaf(p2, d3, p3 * d2);                                    \
        float N   = fmaf(N01, D23, N23 * D01);                                \
        ACC = fmaf(N, __builtin_amdgcn_rcpf(D01 * D23), ACC);                 \
    }
#define PROC(KV, T0, T1, T2, T3, VV)                                          \
    QSTEP(ac0, KV, T0, VV) QSTEP(ac1, KV, T1, VV)                             \
    QSTEP(ac2, KV, T2, VV) QSTEP(ac3, KV, T3, VV)

    for (int g = 0; g < 64; g += 4) {
        if (g + 4 < 64) {   // next group's kv loads, ~770 issue-cycles ahead
            nk0 = kp[(long)(g + 4) * PR4];
            nk1 = kp[(long)(g + 5) * PR4];
            nk2 = kp[(long)(g + 6) * PR4];
            nk3 = kp[(long)(g + 7) * PR4];
        }
        // sub-step 0: fetch hc=g+1 into B, compute hc=g with A
        tB0 = sOp[g + 1]; tB1 = sOp[64 + g + 1]; tB2 = sOp[128 + g + 1];
        tB3 = sOp[192 + g + 1]; vB = sOp[256 + g + 1];
        PROC(kv0, tA0, tA1, tA2, tA3, vA)
        // sub-step 1: fetch hc=g+2 into A, compute hc=g+1 with B
        tA0 = sOp[g + 2]; tA1 = sOp[64 + g + 2]; tA2 = sOp[128 + g + 2];
        tA3 = sOp[192 + g + 2]; vA = sOp[256 + g + 2];
        PROC(kv1, tB0, tB1, tB2, tB3, vB)
        // sub-step 2: fetch hc=g+3 into B, compute hc=g+2 with A
        tB0 = sOp[g + 3]; tB1 = sOp[64 + g + 3]; tB2 = sOp[128 + g + 3];
        tB3 = sOp[192 + g + 3]; vB = sOp[256 + g + 3];
        PROC(kv2, tA0, tA1, tA2, tA3, vA)
        // sub-step 3: fetch hc=g+4 into A (wrap-safe), compute hc=g+3 with B
        {
            const int gn = (g + 4) & 63;
            tA0 = sOp[gn]; tA1 = sOp[64 + gn]; tA2 = sOp[128 + gn];
            tA3 = sOp[192 + gn]; vA = sOp[256 + gn];
        }
        PROC(kv3, tB0, tB1, tB2, tB3, vB)
        kv0 = nk0; kv1 = nk1; kv2 = nk2; kv3 = nk3;
    }
#undef PROC
#undef QSTEP

    // ---- log-softmax over k, no max pass (|val| <= sum|v| ~ 8, fp32-safe) ----
    __shared__ float red[8][4];
    const int lane = k & 63, wv = k >> 6;
    float acc[4] = {ac0, ac1, ac2, ac3};

    #pragma unroll
    for (int j = 0; j < 4; ++j) {
        float e = __builtin_amdgcn_exp2f(acc[j] * 1.4426950408889634f);
        #pragma unroll
        for (int o = 32; o; o >>= 1) e += __shfl_xor(e, o, 64);
        if (lane == 0) red[wv][j] = e;
    }
    __syncthreads();
    #pragma unroll
    for (int j = 0; j < 4; ++j) {
        float s = 0.f;
        #pragma unroll
        for (int w = 0; w < 8; ++w) s += red[w][j];
        float l = __builtin_amdgcn_logf(s) * 0.6931471805599453f;  // ln(s)
        out[((long)b * NQ_ + q0 + j) * NK_ + k] = acc[j] - l;
    }
}

extern "C" void kernel_launch(void* const* d_in, const int* in_sizes, int n_in,
                              void* d_out, int out_size, void* d_ws, size_t ws_size,
                              hipStream_t stream)
{
    const float* xq = (const float*)d_in[0];  // (4,256,256)
    const float* xk = (const float*)d_in[1];  // (4,512,256)
    const float* w1 = (const float*)d_in[2];  // (256,256) out,in
    const float* w2 = (const float*)d_in[3];  // (256,256)
    const float* v  = (const float*)d_in[4];  // (1,256)
    float* out = (float*)d_out;

    float* ktTan = (float*)d_ws;                          // [4][64][2064] ~ 2.1 MB
    float* tbT   = ktTan + (size_t)B_ * 64 * PADROW;      // [4][256][256]  = 1 MB

    gemm_fused<<<dim3(384), 256, 0, stream>>>(xq, xk, w1, w2, ktTan, tbT);
    attn_main<<<dim3(NQ_ / 4, B_), 512, 0, stream>>>(
        (const float4*)ktTan, (const float4*)tbT, (const float4*)v, out);
}

// Round 10
// 43.271 us; speedup vs baseline: 1.0164x; 1.0164x over previous
//
#include <hip/hip_runtime.h>

#define B_  4
#define NQ_ 256
#define NK_ 512
#define H_  256
#define PADK 516   // half8s per kt row (512 + pad): row stride 8256B, not 8KB

typedef _Float16 half8 __attribute__((ext_vector_type(8)));
typedef _Float16 half4_t __attribute__((ext_vector_type(4)));

// tanh via exp2; clamp to +-0.99951172 (largest fp16 < 1) so after fp16
// rounding |ta| <= 0.99951172 and 1 + ta*tb >= 4.88e-4 > 0 always.
#define TWO_LOG2E 2.8853900817779268f
__device__ __forceinline__ float tanh_fast(float x) {
    float t = __builtin_amdgcn_exp2f(x * TWO_LOG2E);
    float r = __builtin_amdgcn_rcpf(t + 1.0f);
    float y = fmaf(-2.0f, r, 1.0f);
    return fminf(fmaxf(y, -0.99951172f), 0.99951172f);
}

// Both GEMMs in one launch, 64x64 tiles, 256 threads, 16 outputs/thread,
// register-double-buffered staging.
// blocks [0,128):  kt[b][o][k] -> ktH[b][o>>3][k][o&7] = fp16(tanh(kt))
// blocks [128,192): qt[b][q][o] -> tbT[b][q][o] = f32 tanh(qt)
__global__ __launch_bounds__(256)
void gemm_fused(const float* __restrict__ xq, const float* __restrict__ xk,
                const float* __restrict__ w1, const float* __restrict__ w2,
                _Float16* __restrict__ ktH,   // [B][32][PADK][8] halves
                float* __restrict__ tbT)      // [B][NQ][H]
{
    constexpr int BK = 32;
    const float* A; const float* Bm;
    int m0, n0, bz; bool iskt;
    {
        int id = blockIdx.x;
        if (id < 128) {                      // kt: M=H(o), N=NK(k)
            iskt = true;
            bz = id >> 5; int t = id & 31;
            m0 = (t >> 3) * 64; n0 = (t & 7) * 64;
            A = w1; Bm = xk + (long)bz * NK_ * H_;
        } else {                             // qt: M=NQ(q), N=H(o)
            iskt = false;
            id -= 128;
            bz = id >> 4; int t = id & 15;
            m0 = (t >> 2) * 64; n0 = (t & 3) * 64;
            A = xq + (long)bz * NQ_ * H_; Bm = w2;
        }
    }
    const int lda = H_, ldb = H_;

    __shared__ float As[BK][68];
    __shared__ float Bs[BK][68];

    const int tid  = threadIdx.x;
    const int lrow = tid >> 2;          // 0..63
    const int lk   = (tid & 3) * 8;     // {0,8,16,24}
    const int tm   = (tid >> 4) * 4;
    const int tn   = (tid & 15) * 4;

    float acc[4][4] = {};

    float4 a0_r = *(const float4*)&A [(long)(m0 + lrow) * lda + lk];
    float4 a1_r = *(const float4*)&A [(long)(m0 + lrow) * lda + lk + 4];
    float4 b0_r = *(const float4*)&Bm[(long)(n0 + lrow) * ldb + lk];
    float4 b1_r = *(const float4*)&Bm[(long)(n0 + lrow) * ldb + lk + 4];
    float4 a0_n = a0_r, a1_n = a1_r, b0_n = b0_r, b1_n = b1_r;

    for (int kt = 0; kt < H_; kt += BK) {
        __syncthreads();
        As[lk+0][lrow]=a0_r.x; As[lk+1][lrow]=a0_r.y; As[lk+2][lrow]=a0_r.z; As[lk+3][lrow]=a0_r.w;
        As[lk+4][lrow]=a1_r.x; As[lk+5][lrow]=a1_r.y; As[lk+6][lrow]=a1_r.z; As[lk+7][lrow]=a1_r.w;
        Bs[lk+0][lrow]=b0_r.x; Bs[lk+1][lrow]=b0_r.y; Bs[lk+2][lrow]=b0_r.z; Bs[lk+3][lrow]=b0_r.w;
        Bs[lk+4][lrow]=b1_r.x; Bs[lk+5][lrow]=b1_r.y; Bs[lk+6][lrow]=b1_r.z; Bs[lk+7][lrow]=b1_r.w;
        if (kt + BK < H_) {
            a0_n = *(const float4*)&A [(long)(m0 + lrow) * lda + kt + BK + lk];
            a1_n = *(const float4*)&A [(long)(m0 + lrow) * lda + kt + BK + lk + 4];
            b0_n = *(const float4*)&Bm[(long)(n0 + lrow) * ldb + kt + BK + lk];
            b1_n = *(const float4*)&Bm[(long)(n0 + lrow) * ldb + kt + BK + lk + 4];
        }
        __syncthreads();
        #pragma unroll
        for (int kk = 0; kk < BK; ++kk) {
            float4 av = *(const float4*)&As[kk][tm];
            float4 bv = *(const float4*)&Bs[kk][tn];
            float am[4] = {av.x, av.y, av.z, av.w};
            float bn[4] = {bv.x, bv.y, bv.z, bv.w};
            #pragma unroll
            for (int i = 0; i < 4; ++i)
                #pragma unroll
                for (int j = 0; j < 4; ++j)
                    acc[i][j] = fmaf(am[i], bn[j], acc[i][j]);
        }
        a0_r = a0_n; a1_r = a1_n; b0_r = b0_n; b1_r = b1_n;
    }

    if (iskt) {
        // o rows m0+tm..+3 are inside 8-group g8=(m0+tm)>>3 at offset tm&7 in {0,4}
        const long gbase = ((long)bz * 32 + ((m0 + tm) >> 3)) * PADK * 8 + (tm & 7);
        #pragma unroll
        for (int j = 0; j < 4; ++j) {
            half4_t h4 = { (_Float16)tanh_fast(acc[0][j]), (_Float16)tanh_fast(acc[1][j]),
                           (_Float16)tanh_fast(acc[2][j]), (_Float16)tanh_fast(acc[3][j]) };
            *(half4_t*)&ktH[gbase + (long)(n0 + tn + j) * 8] = h4;
        }
    } else {
        #pragma unroll
        for (int i = 0; i < 4; ++i) {
            float4 t4 = { tanh_fast(acc[i][0]), tanh_fast(acc[i][1]),
                          tanh_fast(acc[i][2]), tanh_fast(acc[i][3]) };
            *(float4*)&tbT[((long)bz * NQ_ + m0 + tm + i) * H_ + n0 + tn] = t4;
        }
    }
}

// One block per (b, 4 q-rows), 512 threads = one per k. kv is fp16 half8:
// ONE 16B load per 8 h (was 2) -- halves L2 request count and bytes, the one
// resource unchanged across rounds 4-9's null results. Math in f32:
// term = v*(ta+tb)/(1+ta*tb), 4 terms share one rcp via common denominator.
__global__ __launch_bounds__(512, 1)
void attn_main(const half8* __restrict__ ktH,  // [B][32][PADK]
               const float4* __restrict__ tbT, // [B][NQ][H/4]
               const float4* __restrict__ v4p, // [H/4]
               float* __restrict__ out)        // [B][NQ][NK]
{
    const int k = threadIdx.x, b = blockIdx.y, q0 = blockIdx.x * 4;

    __shared__ float4 sT[4][64];
    __shared__ float4 sV[64];
    if (k < 256) {
        const int q = k >> 6, idx = k & 63;
        sT[q][idx] = tbT[((long)b * NQ_ + q0 + q) * 64 + idx];
    } else if (k < 320) {
        sV[k & 63] = v4p[k & 63];
    }
    __syncthreads();

    const half8* kp = ktH + (long)b * 32 * PADK + k;

    float ac0 = 0.f, ac1 = 0.f, ac2 = 0.f, ac3 = 0.f;

    half8 kv0 = kp[0 * PADK], kv1 = kp[1 * PADK],
          kv2 = kp[2 * PADK], kv3 = kp[3 * PADK];
    half8 nk0 = kv0, nk1 = kv1, nk2 = kv2, nk3 = kv3;

#define QSTEP(ACC, A0, A1, A2, A3, TB, VV)                                    \
    {                                                                         \
        float d0 = fmaf(A0, TB.x, 1.f), d1 = fmaf(A1, TB.y, 1.f);             \
        float d2 = fmaf(A2, TB.z, 1.f), d3 = fmaf(A3, TB.w, 1.f);             \
        float p0 = VV.x * (A0 + TB.x), p1 = VV.y * (A1 + TB.y);               \
        float p2 = VV.z * (A2 + TB.z), p3 = VV.w * (A3 + TB.w);               \
        float D01 = d0 * d1, D23 = d2 * d3;                                   \
        float N01 = fmaf(p0, d1, p1 * d0);                                    \
        float N23 = fmaf(p2, d3, p3 * d2);                                    \
        ACC = fmaf(fmaf(N01, D23, N23 * D01),                                 \
                   __builtin_amdgcn_rcpf(D01 * D23), ACC);                    \
    }
#define PROC8(KV, G)                                                          \
    {                                                                         \
        float f0 = (float)KV[0], f1 = (float)KV[1], f2 = (float)KV[2],        \
              f3 = (float)KV[3], f4 = (float)KV[4], f5 = (float)KV[5],        \
              f6 = (float)KV[6], f7 = (float)KV[7];                           \
        float4 va = sV[2 * (G)], vb = sV[2 * (G) + 1];                        \
        float4 t0a = sT[0][2 * (G)], t0b = sT[0][2 * (G) + 1];                \
        QSTEP(ac0, f0, f1, f2, f3, t0a, va)                                   \
        QSTEP(ac0, f4, f5, f6, f7, t0b, vb)                                   \
        float4 t1a = sT[1][2 * (G)], t1b = sT[1][2 * (G) + 1];                \
        QSTEP(ac1, f0, f1, f2, f3, t1a, va)                                   \
        QSTEP(ac1, f4, f5, f6, f7, t1b, vb)                                   \
        float4 t2a = sT[2][2 * (G)], t2b = sT[2][2 * (G) + 1];                \
        QSTEP(ac2, f0, f1, f2, f3, t2a, va)                                   \
        QSTEP(ac2, f4, f5, f6, f7, t2b, vb)                                   \
        float4 t3a = sT[3][2 * (G)], t3b = sT[3][2 * (G) + 1];                \
        QSTEP(ac3, f0, f1, f2, f3, t3a, va)                                   \
        QSTEP(ac3, f4, f5, f6, f7, t3b, vb)                                   \
    }

    for (int g = 0; g < 32; g += 4) {
        if (g + 4 < 32) {
            nk0 = kp[(long)(g + 4) * PADK];
            nk1 = kp[(long)(g + 5) * PADK];
            nk2 = kp[(long)(g + 6) * PADK];
            nk3 = kp[(long)(g + 7) * PADK];
        }
        PROC8(kv0, g + 0)
        PROC8(kv1, g + 1)
        PROC8(kv2, g + 2)
        PROC8(kv3, g + 3)
        kv0 = nk0; kv1 = nk1; kv2 = nk2; kv3 = nk3;
    }
#undef PROC8
#undef QSTEP

    // ---- log-softmax over k, no max pass (|val| <= sum|v| ~ 8, fp32-safe) ----
    __shared__ float red[8][4];
    const int lane = k & 63, wv = k >> 6;
    float acc[4] = {ac0, ac1, ac2, ac3};

    #pragma unroll
    for (int j = 0; j < 4; ++j) {
        float e = __builtin_amdgcn_exp2f(acc[j] * 1.4426950408889634f);
        #pragma unroll
        for (int o = 32; o; o >>= 1) e += __shfl_xor(e, o, 64);
        if (lane == 0) red[wv][j] = e;
    }
    __syncthreads();
    #pragma unroll
    for (int j = 0; j < 4; ++j) {
        float s = 0.f;
        #pragma unroll
        for (int w = 0; w < 8; ++w) s += red[w][j];
        float l = __builtin_amdgcn_logf(s) * 0.6931471805599453f;  // ln(s)
        out[((long)b * NQ_ + q0 + j) * NK_ + k] = acc[j] - l;
    }
}

extern "C" void kernel_launch(void* const* d_in, const int* in_sizes, int n_in,
                              void* d_out, int out_size, void* d_ws, size_t ws_size,
                              hipStream_t stream)
{
    const float* xq = (const float*)d_in[0];  // (4,256,256)
    const float* xk = (const float*)d_in[1];  // (4,512,256)
    const float* w1 = (const float*)d_in[2];  // (256,256) out,in
    const float* w2 = (const float*)d_in[3];  // (256,256)
    const float* v  = (const float*)d_in[4];  // (1,256)
    float* out = (float*)d_out;

    _Float16* ktH = (_Float16*)d_ws;                      // [4][32][516][8] fp16 ~1.06MB
    float* tbT = (float*)((char*)d_ws + (size_t)B_ * 32 * PADK * 8 * 2);  // 1MB f32

    gemm_fused<<<dim3(192), 256, 0, stream>>>(xq, xk, w1, w2, ktH, tbT);
    attn_main<<<dim3(NQ_ / 4, B_), 512, 0, stream>>>(
        (const half8*)ktH, (const float4*)tbT, (const float4*)v, out);
}